// Round 1
// baseline (297.456 us; speedup 1.0000x reference)
//
#include <hip/hip_runtime.h>
#include <hip/hip_bf16.h>

#define NPOS 4096

typedef __attribute__((ext_vector_type(4))) float f32x4;
typedef __attribute__((ext_vector_type(8))) short bf16x8;

__device__ __forceinline__ short f2bf(float f) {
  union { __hip_bfloat16 h; short s; } u;
  u.h = __float2bfloat16(f);
  return u.s;
}

// ---------------- kernel 1: groupnorm stats ----------------
// 128 blocks = (b=4) x (groups=32). Each group = 2 contiguous channels x 4096 = 8192 floats contiguous.
__global__ __launch_bounds__(256) void stats_kernel(const float* __restrict__ x,
                                                    float* __restrict__ stats) {
  const int bg = blockIdx.x;
  const f32x4* base = (const f32x4*)(x + (size_t)bg * 8192);
  float s = 0.f, ss = 0.f;
  for (int i = threadIdx.x; i < 2048; i += 256) {
    f32x4 v = base[i];
    s  += v.x + v.y + v.z + v.w;
    ss += v.x * v.x + v.y * v.y + v.z * v.z + v.w * v.w;
  }
  for (int off = 32; off; off >>= 1) {
    s  += __shfl_down(s, off, 64);
    ss += __shfl_down(ss, off, 64);
  }
  __shared__ float red[8];
  const int wave = threadIdx.x >> 6, lane = threadIdx.x & 63;
  if (lane == 0) { red[wave] = s; red[4 + wave] = ss; }
  __syncthreads();
  if (threadIdx.x == 0) {
    float S  = red[0] + red[1] + red[2] + red[3];
    float SS = red[4] + red[5] + red[6] + red[7];
    float mean = S * (1.f / 8192.f);
    float var  = SS * (1.f / 8192.f) - mean * mean;
    stats[2 * bg]     = mean;
    stats[2 * bg + 1] = rsqrtf(var + 1e-5f);
  }
}

// ---------------- kernel 2: groupnorm + qkv 1x1 convs ----------------
// grid = 192: blk/64 = tensor (0=q,1=k,2=v), rem: b = rem>>4, p0 = (rem&15)*256.
// q,k written transposed [b][pos][ch] bf16 (MFMA-fragment friendly); v written [b][ch][pos] bf16.
__global__ __launch_bounds__(256) void qkv_kernel(
    const float* __restrict__ x,
    const float* __restrict__ Wq, const float* __restrict__ bq,
    const float* __restrict__ Wk, const float* __restrict__ bk,
    const float* __restrict__ Wv, const float* __restrict__ bv,
    const float* __restrict__ gamma, const float* __restrict__ beta,
    const float* __restrict__ stats,
    short* __restrict__ qT, short* __restrict__ kT, short* __restrict__ vC) {
  __shared__ short sbuf[64 * 258];  // [o][pos], pad 2 to dodge bank conflicts
  const int tid = threadIdx.x;
  const int t   = blockIdx.x >> 6;          // 0=q 1=k 2=v
  const int rem = blockIdx.x & 63;
  const int b   = rem >> 4;
  const int p0  = (rem & 15) << 8;
  const int p   = p0 + tid;

  const float* W    = (t == 0) ? Wq : (t == 1) ? Wk : Wv;
  const float* bias = (t == 0) ? bq : (t == 1) ? bk : bv;

  // load + normalize this thread's position column (64 channels)
  float xn[64];
  const float* xb = x + (size_t)b * 64 * NPOS;
  const float* st = stats + b * 64;
#pragma unroll
  for (int c = 0; c < 64; c++) {
    float mean = st[2 * (c >> 1)];
    float rstd = st[2 * (c >> 1) + 1];
    xn[c] = (xb[(size_t)c * NPOS + p] - mean) * rstd * gamma[c] + beta[c];
  }

  if (t == 2) {
    // v: direct coalesced write [b][o][p]
#pragma unroll 1
    for (int o = 0; o < 64; o++) {
      float acc = bias[o];
      const float* wr = W + o * 64;
#pragma unroll
      for (int c = 0; c < 64; c++) acc = fmaf(wr[c], xn[c], acc);
      vC[((size_t)(b * 64 + o)) * NPOS + p] = f2bf(acc);
    }
    return;
  }

  short* dst = ((t == 0) ? qT : kT) + ((size_t)(b * NPOS + p0)) * 64;
#pragma unroll 1
  for (int o = 0; o < 64; o++) {
    float acc = bias[o];
    const float* wr = W + o * 64;
#pragma unroll
    for (int c = 0; c < 64; c++) acc = fmaf(wr[c], xn[c], acc);
    sbuf[o * 258 + tid] = f2bf(acc);
  }
  __syncthreads();
  // transpose out: write [pos][ch] rows coalesced, 16B per lane
#pragma unroll 1
  for (int i = tid; i < 2048; i += 256) {
    int pos = i >> 3, c0 = (i & 7) << 3;
    bf16x8 v;
#pragma unroll
    for (int m = 0; m < 8; m++) v[m] = sbuf[(c0 + m) * 258 + pos];
    *(bf16x8*)(dst + (size_t)pos * 64 + c0) = v;
  }
}

// ---------------- kernel 3: flash attention ----------------
// 256 blocks = b x (4096/64 Q-tiles). 4 waves/block, 16 Q rows per wave.
// mfma_f32_16x16x32_bf16 layouts (verified, guide §3):
//   A: lane holds A[m=lane&15][k=quad*8+j], j=0..7
//   B: lane holds B[k=quad*8+j][n=lane&15]
//   C/D: lane holds D[row=quad*4+reg][col=lane&15]
#define KS 72  // LDS row stride in bf16 (16B-aligned rows, conflict-benign)
__global__ __launch_bounds__(256) void flash_kernel(
    const short* __restrict__ qT, const short* __restrict__ kT,
    const short* __restrict__ vC, float* __restrict__ outT) {
  __shared__ short K_lds[64 * KS];       // [j][c]
  __shared__ short V_lds[64 * KS];       // [c][j]
  __shared__ short P_lds[4 * 16 * KS];   // per-wave [m][j]

  const int blk  = blockIdx.x;
  const int b    = blk >> 6;
  const int q0   = (blk & 63) << 6;
  const int tid  = threadIdx.x;
  const int wave = tid >> 6;
  const int lane = tid & 63;
  const int quad = lane >> 4;
  const int l16  = lane & 15;
  const float scale = 0.125f;  // 1/sqrt(64)

  // Q A-fragments: rows m = q0 + wave*16 + l16, k = kstep*32 + quad*8 + j
  const short* qbase = qT + ((size_t)(b * NPOS + q0 + wave * 16 + l16)) * 64;
  bf16x8 a0 = *(const bf16x8*)(qbase + quad * 8);
  bf16x8 a1 = *(const bf16x8*)(qbase + 32 + quad * 8);

  const f32x4 zero4 = {0.f, 0.f, 0.f, 0.f};
  f32x4 o_acc[4] = {zero4, zero4, zero4, zero4};
  float m_i[4], l_i[4];
#pragma unroll
  for (int r = 0; r < 4; r++) { m_i[r] = -1e30f; l_i[r] = 0.f; }

  for (int kt = 0; kt < 64; kt++) {
    const int j0 = kt * 64;
    __syncthreads();
    {
      // stage K tile [j][c] and V tile [c][j]; thread -> row tid>>2, 16 shorts at (tid&3)*16
      const int r  = tid >> 2;
      const int cc = (tid & 3) << 4;
      const bf16x8* ksrc = (const bf16x8*)(kT + ((size_t)(b * NPOS + j0 + r)) * 64 + cc);
      bf16x8* kdst = (bf16x8*)(K_lds + r * KS + cc);
      kdst[0] = ksrc[0]; kdst[1] = ksrc[1];
      const bf16x8* vsrc = (const bf16x8*)(vC + ((size_t)(b * 64 + r)) * NPOS + j0 + cc);
      bf16x8* vdst = (bf16x8*)(V_lds + r * KS + cc);
      vdst[0] = vsrc[0]; vdst[1] = vsrc[1];
    }
    __syncthreads();

    // S = Q^T K : 4 N-tiles of 16 cols, K=64 channels in 2 mfma steps
    f32x4 s[4] = {zero4, zero4, zero4, zero4};
#pragma unroll
    for (int n = 0; n < 4; n++) {
      const short* kr = K_lds + (n * 16 + l16) * KS;
      bf16x8 b0 = *(const bf16x8*)(kr + quad * 8);
      bf16x8 b1 = *(const bf16x8*)(kr + 32 + quad * 8);
      s[n] = __builtin_amdgcn_mfma_f32_16x16x32_bf16(a0, b0, s[n], 0, 0, 0);
      s[n] = __builtin_amdgcn_mfma_f32_16x16x32_bf16(a1, b1, s[n], 0, 0, 0);
    }

    // online softmax; row = quad*4 + r lives in this lane's 16-lane group
    float rmax[4];
#pragma unroll
    for (int r = 0; r < 4; r++)
      rmax[r] = fmaxf(fmaxf(s[0][r], s[1][r]), fmaxf(s[2][r], s[3][r]));
#pragma unroll
    for (int off = 1; off < 16; off <<= 1) {
#pragma unroll
      for (int r = 0; r < 4; r++) rmax[r] = fmaxf(rmax[r], __shfl_xor(rmax[r], off, 64));
    }
    float alpha[4], m_new[4];
#pragma unroll
    for (int r = 0; r < 4; r++) {
      float mn = fmaxf(m_i[r], rmax[r] * scale);
      alpha[r] = __expf(m_i[r] - mn);
      m_new[r] = mn;
    }
    float rsum[4] = {0.f, 0.f, 0.f, 0.f};
#pragma unroll
    for (int n = 0; n < 4; n++) {
#pragma unroll
      for (int r = 0; r < 4; r++) {
        float pv = __expf(s[n][r] * scale - m_new[r]);
        s[n][r] = pv;
        rsum[r] += pv;
      }
    }
#pragma unroll
    for (int off = 1; off < 16; off <<= 1) {
#pragma unroll
      for (int r = 0; r < 4; r++) rsum[r] += __shfl_xor(rsum[r], off, 64);
    }
#pragma unroll
    for (int r = 0; r < 4; r++) {
      l_i[r] = l_i[r] * alpha[r] + rsum[r];
      m_i[r] = m_new[r];
    }
#pragma unroll
    for (int n = 0; n < 4; n++)
#pragma unroll
      for (int r = 0; r < 4; r++) o_acc[n][r] *= alpha[r];

    // P: C/D layout -> A layout through per-wave-private LDS (wave-internal dep, no barrier)
    short* pw = P_lds + wave * 16 * KS;
#pragma unroll
    for (int n = 0; n < 4; n++)
#pragma unroll
      for (int r = 0; r < 4; r++)
        pw[(quad * 4 + r) * KS + n * 16 + l16] = f2bf(s[n][r]);

    const short* pr = pw + l16 * KS;
    bf16x8 pa0 = *(const bf16x8*)(pr + quad * 8);
    bf16x8 pa1 = *(const bf16x8*)(pr + 32 + quad * 8);

    // O += P @ V^T : N-tiles over channels
#pragma unroll
    for (int n = 0; n < 4; n++) {
      const short* vr = V_lds + (n * 16 + l16) * KS;
      bf16x8 b0 = *(const bf16x8*)(vr + quad * 8);
      bf16x8 b1 = *(const bf16x8*)(vr + 32 + quad * 8);
      o_acc[n] = __builtin_amdgcn_mfma_f32_16x16x32_bf16(pa0, b0, o_acc[n], 0, 0, 0);
      o_acc[n] = __builtin_amdgcn_mfma_f32_16x16x32_bf16(pa1, b1, o_acc[n], 0, 0, 0);
    }
  }

  // epilogue: outT[b][row][c] = O / l
#pragma unroll
  for (int r = 0; r < 4; r++) {
    float inv = 1.0f / l_i[r];
    int row = q0 + wave * 16 + quad * 4 + r;
    float* dst = outT + ((size_t)(b * NPOS + row)) * 64;
#pragma unroll
    for (int n = 0; n < 4; n++) dst[n * 16 + l16] = o_acc[n][r] * inv;
  }
}

// ---------------- kernel 4: output conv + residual ----------------
__global__ __launch_bounds__(256) void oconv_kernel(
    const float* __restrict__ outT, const float* __restrict__ Wo,
    const float* __restrict__ bo, const float* __restrict__ x,
    float* __restrict__ y) {
  const int b = blockIdx.x >> 4;
  const int p = ((blockIdx.x & 15) << 8) + threadIdx.x;
  float oc[64];
  const f32x4* src = (const f32x4*)(outT + ((size_t)(b * NPOS + p)) * 64);
#pragma unroll
  for (int i = 0; i < 16; i++) {
    f32x4 v = src[i];
    oc[4 * i] = v.x; oc[4 * i + 1] = v.y; oc[4 * i + 2] = v.z; oc[4 * i + 3] = v.w;
  }
  const float* xb = x + (size_t)b * 64 * NPOS;
  float* yb = y + (size_t)b * 64 * NPOS;
#pragma unroll 1
  for (int o = 0; o < 64; o++) {
    float acc = bo[o];
    const float* wr = Wo + o * 64;
#pragma unroll
    for (int c = 0; c < 64; c++) acc = fmaf(wr[c], oc[c], acc);
    yb[(size_t)o * NPOS + p] = xb[(size_t)o * NPOS + p] + acc;
  }
}

// ---------------- launcher ----------------
extern "C" void kernel_launch(void* const* d_in, const int* in_sizes, int n_in,
                              void* d_out, int out_size, void* d_ws, size_t ws_size,
                              hipStream_t stream) {
  const float* x     = (const float*)d_in[0];
  const float* Wq    = (const float*)d_in[1];
  const float* bq    = (const float*)d_in[2];
  const float* Wk    = (const float*)d_in[3];
  const float* bk    = (const float*)d_in[4];
  const float* Wv    = (const float*)d_in[5];
  const float* bv    = (const float*)d_in[6];
  const float* Wo    = (const float*)d_in[7];
  const float* bo    = (const float*)d_in[8];
  const float* gamma = (const float*)d_in[9];
  const float* beta  = (const float*)d_in[10];
  float* y = (float*)d_out;

  char* ws = (char*)d_ws;
  float* stats = (float*)ws;                               // 256 floats
  short* qT   = (short*)(ws + 1024);                       // 2 MB
  short* kT   = (short*)(ws + 1024 + (1u << 21));          // 2 MB
  short* vC   = (short*)(ws + 1024 + (2u << 21));          // 2 MB
  float* outT = (float*)(ws + 1024 + (3u << 21));          // 4 MB

  stats_kernel<<<dim3(128), dim3(256), 0, stream>>>(x, stats);
  qkv_kernel<<<dim3(192), dim3(256), 0, stream>>>(x, Wq, bq, Wk, bk, Wv, bv,
                                                  gamma, beta, stats, qT, kT, vC);
  flash_kernel<<<dim3(256), dim3(256), 0, stream>>>(qT, kT, vC, outT);
  oconv_kernel<<<dim3(64), dim3(256), 0, stream>>>(outT, Wo, bo, x, y);
}

// Round 2
// 195.103 us; speedup vs baseline: 1.5246x; 1.5246x over previous
//
#include <hip/hip_runtime.h>
#include <hip/hip_bf16.h>

#define NPOS 4096
#define KS 72  // LDS row stride in bf16 shorts (16B-aligned rows)

typedef __attribute__((ext_vector_type(4))) float f32x4;
typedef __attribute__((ext_vector_type(8))) short bf16x8;
typedef __attribute__((ext_vector_type(2))) int i32x2;

__device__ __forceinline__ short f2bf(float f) {
  union { __hip_bfloat16 h; short s; } u;
  u.h = __float2bfloat16(f);
  return u.s;
}
__device__ __forceinline__ int pack_bf16(float lo, float hi) {
  unsigned a = (unsigned short)f2bf(lo);
  unsigned b = (unsigned short)f2bf(hi);
  return (int)(a | (b << 16));
}

// ---------------- kernel 1: groupnorm stats ----------------
__global__ __launch_bounds__(256) void stats_kernel(const float* __restrict__ x,
                                                    float* __restrict__ stats) {
  const int bg = blockIdx.x;
  const f32x4* base = (const f32x4*)(x + (size_t)bg * 8192);
  float s = 0.f, ss = 0.f;
  for (int i = threadIdx.x; i < 2048; i += 256) {
    f32x4 v = base[i];
    s  += v.x + v.y + v.z + v.w;
    ss += v.x * v.x + v.y * v.y + v.z * v.z + v.w * v.w;
  }
  for (int off = 32; off; off >>= 1) {
    s  += __shfl_down(s, off, 64);
    ss += __shfl_down(ss, off, 64);
  }
  __shared__ float red[8];
  const int wave = threadIdx.x >> 6, lane = threadIdx.x & 63;
  if (lane == 0) { red[wave] = s; red[4 + wave] = ss; }
  __syncthreads();
  if (threadIdx.x == 0) {
    float S  = red[0] + red[1] + red[2] + red[3];
    float SS = red[4] + red[5] + red[6] + red[7];
    float mean = S * (1.f / 8192.f);
    float var  = SS * (1.f / 8192.f) - mean * mean;
    stats[2 * bg]     = mean;
    stats[2 * bg + 1] = rsqrtf(var + 1e-5f);
  }
}

// ---------------- kernel 2: groupnorm + qkv 1x1 convs ----------------
// q,k -> [b][pos][ch] bf16; v -> [b][ch][pos] bf16.
__global__ __launch_bounds__(256) void qkv_kernel(
    const float* __restrict__ x,
    const float* __restrict__ Wq, const float* __restrict__ bq,
    const float* __restrict__ Wk, const float* __restrict__ bk,
    const float* __restrict__ Wv, const float* __restrict__ bv,
    const float* __restrict__ gamma, const float* __restrict__ beta,
    const float* __restrict__ stats,
    short* __restrict__ qT, short* __restrict__ kT, short* __restrict__ vC) {
  __shared__ short sbuf[64 * 258];
  const int tid = threadIdx.x;
  const int t   = blockIdx.x >> 6;  // 0=q 1=k 2=v
  const int rem = blockIdx.x & 63;
  const int b   = rem >> 4;
  const int p0  = (rem & 15) << 8;
  const int p   = p0 + tid;

  const float* W    = (t == 0) ? Wq : (t == 1) ? Wk : Wv;
  const float* bias = (t == 0) ? bq : (t == 1) ? bk : bv;

  float xn[64];
  const float* xb = x + (size_t)b * 64 * NPOS;
  const float* st = stats + b * 64;
#pragma unroll
  for (int c = 0; c < 64; c++) {
    float mean = st[2 * (c >> 1)];
    float rstd = st[2 * (c >> 1) + 1];
    xn[c] = (xb[(size_t)c * NPOS + p] - mean) * rstd * gamma[c] + beta[c];
  }

  if (t == 2) {
#pragma unroll 1
    for (int o = 0; o < 64; o++) {
      const float* wr = W + o * 64;
      float a0 = 0.f, a1 = 0.f, a2 = 0.f, a3 = 0.f;
#pragma unroll
      for (int c = 0; c < 16; c++) {
        a0 = fmaf(wr[c],      xn[c],      a0);
        a1 = fmaf(wr[16 + c], xn[16 + c], a1);
        a2 = fmaf(wr[32 + c], xn[32 + c], a2);
        a3 = fmaf(wr[48 + c], xn[48 + c], a3);
      }
      vC[((size_t)(b * 64 + o)) * NPOS + p] = f2bf(bias[o] + ((a0 + a1) + (a2 + a3)));
    }
    return;
  }

  short* dst = ((t == 0) ? qT : kT) + ((size_t)(b * NPOS + p0)) * 64;
#pragma unroll 1
  for (int o = 0; o < 64; o++) {
    const float* wr = W + o * 64;
    float a0 = 0.f, a1 = 0.f, a2 = 0.f, a3 = 0.f;
#pragma unroll
    for (int c = 0; c < 16; c++) {
      a0 = fmaf(wr[c],      xn[c],      a0);
      a1 = fmaf(wr[16 + c], xn[16 + c], a1);
      a2 = fmaf(wr[32 + c], xn[32 + c], a2);
      a3 = fmaf(wr[48 + c], xn[48 + c], a3);
    }
    sbuf[o * 258 + tid] = f2bf(bias[o] + ((a0 + a1) + (a2 + a3)));
  }
  __syncthreads();
#pragma unroll 1
  for (int i = tid; i < 2048; i += 256) {
    int pos = i >> 3, c0 = (i & 7) << 3;
    bf16x8 v;
#pragma unroll
    for (int m = 0; m < 8; m++) v[m] = sbuf[(c0 + m) * 258 + pos];
    *(bf16x8*)(dst + (size_t)pos * 64 + c0) = v;
  }
}

// ---------------- kernel 3: split-K flash attention (partials) ----------------
// grid 1024 = b(4) x chunk(4) x qtile(64). Each block: 64 Q rows, 1024 keys (16 kt).
// Computes S^T = K·Q^T so each lane's C-fragment holds one softmax row (m=l16):
//   A: lane holds A[m=l16][k=quad*8+j]; B: lane holds B[k=quad*8+j][n=l16];
//   C/D: lane holds D[row=quad*4+r][col=l16].
// Output O^T[ch][m] partials + (m,l) per row to workspace.
__global__ __launch_bounds__(256, 4) void flash_part_kernel(
    const short* __restrict__ qT, const short* __restrict__ kT,
    const short* __restrict__ vC, float* __restrict__ part,
    float* __restrict__ ml) {
  __shared__ short K_lds[64 * KS];      // [j_local][c]
  __shared__ short V_lds[64 * KS];      // [ch][j_local]
  __shared__ short P_lds[4 * 16 * KS];  // per wave: [m_local(16)][j(64)]

  const int blk   = blockIdx.x;
  const int qt    = blk & 63;
  const int chunk = (blk >> 6) & 3;
  const int b     = blk >> 8;
  const int q0    = qt << 6;
  const int jc    = chunk << 10;
  const int tid   = threadIdx.x;
  const int wave  = tid >> 6;
  const int lane  = tid & 63;
  const int quad  = lane >> 4;
  const int l16   = lane & 15;
  const float scale = 0.125f;

  // Q fragments as B operand: B[k=c][n=m], m = q0 + wave*16 + l16
  const short* qbase = qT + ((size_t)(b * NPOS + q0 + wave * 16 + l16)) * 64;
  bf16x8 bq0 = *(const bf16x8*)(qbase + quad * 8);
  bf16x8 bq1 = *(const bf16x8*)(qbase + 32 + quad * 8);

  const f32x4 zero4 = {0.f, 0.f, 0.f, 0.f};
  f32x4 o_acc[4] = {zero4, zero4, zero4, zero4};  // O^T: ch = t*16+quad*4+r, m = l16
  float m_i = -1e30f, l_i = 0.f;

  for (int kt = 0; kt < 16; kt++) {
    const int j0 = jc + (kt << 6);
    __syncthreads();
    {
      const int r  = tid >> 2;
      const int cc = (tid & 3) << 4;
      const bf16x8* ksrc = (const bf16x8*)(kT + ((size_t)(b * NPOS + j0 + r)) * 64 + cc);
      bf16x8* kdst = (bf16x8*)(K_lds + r * KS + cc);
      kdst[0] = ksrc[0]; kdst[1] = ksrc[1];
      const bf16x8* vsrc = (const bf16x8*)(vC + ((size_t)(b * 64 + r)) * NPOS + j0 + cc);
      bf16x8* vdst = (bf16x8*)(V_lds + r * KS + cc);
      vdst[0] = vsrc[0]; vdst[1] = vsrc[1];
    }
    __syncthreads();

    // S^T tiles: rows j = t*16+quad*4+r, col m = l16
    f32x4 st[4];
#pragma unroll
    for (int t = 0; t < 4; t++) {
      const short* kr = K_lds + (t * 16 + l16) * KS;
      bf16x8 ka0 = *(const bf16x8*)(kr + quad * 8);
      bf16x8 ka1 = *(const bf16x8*)(kr + 32 + quad * 8);
      f32x4 acc = zero4;
      acc = __builtin_amdgcn_mfma_f32_16x16x32_bf16(ka0, bq0, acc, 0, 0, 0);
      acc = __builtin_amdgcn_mfma_f32_16x16x32_bf16(ka1, bq1, acc, 0, 0, 0);
      st[t] = acc;
    }

    // online softmax for row m=l16 (16 j-values per lane, cross-quad reduce)
    float rmax = -1e30f;
#pragma unroll
    for (int t = 0; t < 4; t++)
#pragma unroll
      for (int r = 0; r < 4; r++) rmax = fmaxf(rmax, st[t][r]);
    rmax = fmaxf(rmax, __shfl_xor(rmax, 16, 64));
    rmax = fmaxf(rmax, __shfl_xor(rmax, 32, 64));
    float mn = fmaxf(m_i, rmax * scale);
    float alpha = __expf(m_i - mn);
    float rsum = 0.f;
#pragma unroll
    for (int t = 0; t < 4; t++)
#pragma unroll
      for (int r = 0; r < 4; r++) {
        float pv = __expf(st[t][r] * scale - mn);
        st[t][r] = pv;
        rsum += pv;
      }
    rsum += __shfl_xor(rsum, 16, 64);
    rsum += __shfl_xor(rsum, 32, 64);
    l_i = l_i * alpha + rsum;
    m_i = mn;
#pragma unroll
    for (int t = 0; t < 4; t++) o_acc[t] *= alpha;

    // P -> LDS [m][j]: lane holds 4 consecutive j per t -> one b64 write each
    short* pw = P_lds + wave * 16 * KS;
#pragma unroll
    for (int t = 0; t < 4; t++) {
      i32x2 val;
      val.x = pack_bf16(st[t][0], st[t][1]);
      val.y = pack_bf16(st[t][2], st[t][3]);
      *(i32x2*)(pw + l16 * KS + t * 16 + quad * 4) = val;
    }
    // P^T as B operand: B[k=j][n=m] -> lane reads P[m=l16][j=ks*32+quad*8..]
    const short* pr = pw + l16 * KS;
    bf16x8 pb0 = *(const bf16x8*)(pr + quad * 8);
    bf16x8 pb1 = *(const bf16x8*)(pr + 32 + quad * 8);

    // O^T += V·P^T : A=V[ch][j]
#pragma unroll
    for (int t = 0; t < 4; t++) {
      const short* vr = V_lds + (t * 16 + l16) * KS;
      bf16x8 va0 = *(const bf16x8*)(vr + quad * 8);
      bf16x8 va1 = *(const bf16x8*)(vr + 32 + quad * 8);
      o_acc[t] = __builtin_amdgcn_mfma_f32_16x16x32_bf16(va0, pb0, o_acc[t], 0, 0, 0);
      o_acc[t] = __builtin_amdgcn_mfma_f32_16x16x32_bf16(va1, pb1, o_acc[t], 0, 0, 0);
    }
  }

  // write partials: part[b][chunk][qt][ch(64)][row(64)], ml[b][chunk][qt][2][64]
  const size_t pbase = ((size_t)((b * 4 + chunk) * 64 + qt)) * 4096;
  const int col = wave * 16 + l16;
#pragma unroll
  for (int t = 0; t < 4; t++)
#pragma unroll
    for (int r = 0; r < 4; r++)
      part[pbase + (size_t)(t * 16 + quad * 4 + r) * 64 + col] = o_acc[t][r];
  if (quad == 0) {
    const size_t mlbase = ((size_t)((b * 4 + chunk) * 64 + qt)) * 128;
    ml[mlbase + col]      = m_i;
    ml[mlbase + 64 + col] = l_i;
  }
}

// ---------------- kernel 3b: combine split-K partials ----------------
// grid 256 = b x qtile. Writes outT[b][ch][pos] (coalesced for oconv).
__global__ __launch_bounds__(256) void combine_kernel(
    const float* __restrict__ part, const float* __restrict__ ml,
    float* __restrict__ outT) {
  __shared__ float sm[4][64], sl[4][64], coef[4][64];
  const int b   = blockIdx.x >> 6;
  const int qt  = blockIdx.x & 63;
  const int tid = threadIdx.x;
  {
    const int c = tid >> 6, row = tid & 63;
    const size_t mlbase = ((size_t)((b * 4 + c) * 64 + qt)) * 128;
    sm[c][row] = ml[mlbase + row];
    sl[c][row] = ml[mlbase + 64 + row];
  }
  __syncthreads();
  if (tid < 64) {
    float m0 = sm[0][tid], m1 = sm[1][tid], m2 = sm[2][tid], m3 = sm[3][tid];
    float ms = fmaxf(fmaxf(m0, m1), fmaxf(m2, m3));
    float w0 = __expf(m0 - ms), w1 = __expf(m1 - ms);
    float w2 = __expf(m2 - ms), w3 = __expf(m3 - ms);
    float lt = w0 * sl[0][tid] + w1 * sl[1][tid] + w2 * sl[2][tid] + w3 * sl[3][tid];
    float inv = 1.f / lt;
    coef[0][tid] = w0 * inv; coef[1][tid] = w1 * inv;
    coef[2][tid] = w2 * inv; coef[3][tid] = w3 * inv;
  }
  __syncthreads();
  const int ch = tid >> 2, rs = (tid & 3) << 4;
  float acc[16];
#pragma unroll
  for (int i = 0; i < 16; i++) acc[i] = 0.f;
#pragma unroll
  for (int c = 0; c < 4; c++) {
    const f32x4* src = (const f32x4*)(part +
        ((size_t)((b * 4 + c) * 64 + qt)) * 4096 + (size_t)ch * 64 + rs);
#pragma unroll
    for (int i = 0; i < 4; i++) {
      f32x4 v = src[i];
      acc[4 * i + 0] += coef[c][rs + 4 * i + 0] * v.x;
      acc[4 * i + 1] += coef[c][rs + 4 * i + 1] * v.y;
      acc[4 * i + 2] += coef[c][rs + 4 * i + 2] * v.z;
      acc[4 * i + 3] += coef[c][rs + 4 * i + 3] * v.w;
    }
  }
  float* dst = outT + ((size_t)(b * 64 + ch)) * NPOS + (qt << 6) + rs;
#pragma unroll
  for (int i = 0; i < 4; i++) {
    f32x4 v = {acc[4 * i], acc[4 * i + 1], acc[4 * i + 2], acc[4 * i + 3]};
    *(f32x4*)(dst + 4 * i) = v;
  }
}

// ---------------- kernel 4: output conv + residual ----------------
// grid 256 = b(4) x oseg(4) x ptile(16). outT is [b][ch][pos] -> coalesced reads.
__global__ __launch_bounds__(256) void oconv_kernel(
    const float* __restrict__ outT, const float* __restrict__ Wo,
    const float* __restrict__ bo, const float* __restrict__ x,
    float* __restrict__ y) {
  const int b    = blockIdx.x >> 6;
  const int oseg = (blockIdx.x >> 4) & 3;
  const int p    = ((blockIdx.x & 15) << 8) + threadIdx.x;
  float oc[64];
  const float* src = outT + (size_t)b * 64 * NPOS + p;
#pragma unroll
  for (int c = 0; c < 64; c++) oc[c] = src[(size_t)c * NPOS];
  const float* xb = x + (size_t)b * 64 * NPOS;
  float* yb = y + (size_t)b * 64 * NPOS;
#pragma unroll 1
  for (int i = 0; i < 16; i++) {
    const int o = oseg * 16 + i;
    const float* wr = Wo + o * 64;
    float a0 = 0.f, a1 = 0.f, a2 = 0.f, a3 = 0.f;
#pragma unroll
    for (int c = 0; c < 16; c++) {
      a0 = fmaf(wr[c],      oc[c],      a0);
      a1 = fmaf(wr[16 + c], oc[16 + c], a1);
      a2 = fmaf(wr[32 + c], oc[32 + c], a2);
      a3 = fmaf(wr[48 + c], oc[48 + c], a3);
    }
    yb[(size_t)o * NPOS + p] = xb[(size_t)o * NPOS + p] + bo[o] + ((a0 + a1) + (a2 + a3));
  }
}

// ---------------- launcher ----------------
extern "C" void kernel_launch(void* const* d_in, const int* in_sizes, int n_in,
                              void* d_out, int out_size, void* d_ws, size_t ws_size,
                              hipStream_t stream) {
  const float* x     = (const float*)d_in[0];
  const float* Wq    = (const float*)d_in[1];
  const float* bq    = (const float*)d_in[2];
  const float* Wk    = (const float*)d_in[3];
  const float* bk    = (const float*)d_in[4];
  const float* Wv    = (const float*)d_in[5];
  const float* bv    = (const float*)d_in[6];
  const float* Wo    = (const float*)d_in[7];
  const float* bo    = (const float*)d_in[8];
  const float* gamma = (const float*)d_in[9];
  const float* beta  = (const float*)d_in[10];
  float* y = (float*)d_out;

  char* ws = (char*)d_ws;
  float* stats = (float*)ws;                                   // 1 KB
  short* qT   = (short*)(ws + 1024);                           // 2 MB
  short* kT   = (short*)(ws + 1024 + (1u << 21));              // 2 MB
  short* vC   = (short*)(ws + 1024 + (2u << 21));              // 2 MB
  float* outT = (float*)(ws + 1024 + (3u << 21));              // 4 MB  [b][ch][pos]
  float* part = (float*)(ws + 1024 + (5u << 21));              // 16 MB [b][chunk][qt][ch][row]
  float* ml   = (float*)(ws + 1024 + (13u << 21));             // 512 KB

  stats_kernel<<<dim3(128), dim3(256), 0, stream>>>(x, stats);
  qkv_kernel<<<dim3(192), dim3(256), 0, stream>>>(x, Wq, bq, Wk, bk, Wv, bv,
                                                  gamma, beta, stats, qT, kT, vC);
  flash_part_kernel<<<dim3(1024), dim3(256), 0, stream>>>(qT, kT, vC, part, ml);
  combine_kernel<<<dim3(256), dim3(256), 0, stream>>>(part, ml, outT);
  oconv_kernel<<<dim3(256), dim3(256), 0, stream>>>(outT, Wo, bo, x, y);
}

// Round 3
// 130.038 us; speedup vs baseline: 2.2875x; 1.5004x over previous
//
#include <hip/hip_runtime.h>
#include <hip/hip_bf16.h>

#define NPOS 4096
#define KS 72  // LDS row stride in bf16 shorts (16B-aligned rows)

typedef __attribute__((ext_vector_type(4))) float f32x4;
typedef __attribute__((ext_vector_type(8))) short bf16x8;
typedef __attribute__((ext_vector_type(2))) int i32x2;

__device__ __forceinline__ short f2bf(float f) {
  union { __hip_bfloat16 h; short s; } u;
  u.h = __float2bfloat16(f);
  return u.s;
}
__device__ __forceinline__ int pack_bf16(float lo, float hi) {
  unsigned a = (unsigned short)f2bf(lo);
  unsigned b = (unsigned short)f2bf(hi);
  return (int)(a | (b << 16));
}
__device__ __forceinline__ bf16x8 cvt8(const float* p) {
  f32x4 u = *(const f32x4*)p;
  f32x4 v = *(const f32x4*)(p + 4);
  bf16x8 r;
  r[0] = f2bf(u.x); r[1] = f2bf(u.y); r[2] = f2bf(u.z); r[3] = f2bf(u.w);
  r[4] = f2bf(v.x); r[5] = f2bf(v.y); r[6] = f2bf(v.z); r[7] = f2bf(v.w);
  return r;
}

// ---------------- kernel 1: groupnorm stats ----------------
__global__ __launch_bounds__(256) void stats_kernel(const float* __restrict__ x,
                                                    float* __restrict__ stats) {
  const int bg = blockIdx.x;
  const f32x4* base = (const f32x4*)(x + (size_t)bg * 8192);
  float s = 0.f, ss = 0.f;
  for (int i = threadIdx.x; i < 2048; i += 256) {
    f32x4 v = base[i];
    s  += v.x + v.y + v.z + v.w;
    ss += v.x * v.x + v.y * v.y + v.z * v.z + v.w * v.w;
  }
  for (int off = 32; off; off >>= 1) {
    s  += __shfl_down(s, off, 64);
    ss += __shfl_down(ss, off, 64);
  }
  __shared__ float red[8];
  const int wave = threadIdx.x >> 6, lane = threadIdx.x & 63;
  if (lane == 0) { red[wave] = s; red[4 + wave] = ss; }
  __syncthreads();
  if (threadIdx.x == 0) {
    float S  = red[0] + red[1] + red[2] + red[3];
    float SS = red[4] + red[5] + red[6] + red[7];
    float mean = S * (1.f / 8192.f);
    float var  = SS * (1.f / 8192.f) - mean * mean;
    stats[2 * bg]     = mean;
    stats[2 * bg + 1] = rsqrtf(var + 1e-5f);
  }
}

// ---------------- kernel 2: groupnorm + qkv via MFMA ----------------
// grid 512 = b(4) x pt(128 tiles of 32 pos). Wave w computes out-tile w (16 outs)
// of each of q,k,v. q,k -> [b][pos][ch] bf16; v -> [b][ch][pos] bf16.
__global__ __launch_bounds__(256) void qkv_kernel(
    const float* __restrict__ x,
    const float* __restrict__ Wq, const float* __restrict__ bq,
    const float* __restrict__ Wk, const float* __restrict__ bk,
    const float* __restrict__ Wv, const float* __restrict__ bv,
    const float* __restrict__ gamma, const float* __restrict__ beta,
    const float* __restrict__ stats,
    short* __restrict__ qT, short* __restrict__ kT, short* __restrict__ vC) {
  __shared__ short xn_lds[32 * KS];    // [pos][ch] bf16 (B-fragment layout)
  __shared__ short out_lds[32 * 200];  // [pos][out 0..191 (q|k|v)]

  const int tid  = threadIdx.x;
  const int b    = blockIdx.x >> 7;
  const int pt   = blockIdx.x & 127;
  const int p0   = pt << 5;
  const int wave = tid >> 6;
  const int lane = tid & 63;
  const int quad = lane >> 4;
  const int l16  = lane & 15;

  // --- W fragments: wave w owns rows [w*16, w*16+16) of Wq, Wk, Wv ---
  bf16x8 a_lo[3], a_hi[3];
  float bias_r[3][4];
  {
    const float* Wsrc[3] = {Wq, Wk, Wv};
    const float* Bsrc[3] = {bq, bk, bv};
#pragma unroll
    for (int t = 0; t < 3; t++) {
      const float* wr = Wsrc[t] + (size_t)(wave * 16 + l16) * 64;
      a_lo[t] = cvt8(wr + quad * 8);
      a_hi[t] = cvt8(wr + 32 + quad * 8);
#pragma unroll
      for (int r = 0; r < 4; r++) bias_r[t][r] = Bsrc[t][wave * 16 + quad * 4 + r];
    }
  }

  // --- stage + groupnorm X tile: [64 ch][32 pos] -> xn_lds[pos][ch] bf16 ---
  {
    const int ch = tid >> 2, pg = tid & 3;
    float mean = stats[b * 64 + 2 * (ch >> 1)];
    float rstd = stats[b * 64 + 2 * (ch >> 1) + 1];
    float sc = rstd * gamma[ch];
    float sh = beta[ch] - mean * sc;
    const float* src = x + ((size_t)(b * 64 + ch)) * NPOS + p0 + pg * 8;
    f32x4 v0 = *(const f32x4*)src;
    f32x4 v1 = *(const f32x4*)(src + 4);
    short* d = xn_lds + ch;
    d[(pg * 8 + 0) * KS] = f2bf(fmaf(v0.x, sc, sh));
    d[(pg * 8 + 1) * KS] = f2bf(fmaf(v0.y, sc, sh));
    d[(pg * 8 + 2) * KS] = f2bf(fmaf(v0.z, sc, sh));
    d[(pg * 8 + 3) * KS] = f2bf(fmaf(v0.w, sc, sh));
    d[(pg * 8 + 4) * KS] = f2bf(fmaf(v1.x, sc, sh));
    d[(pg * 8 + 5) * KS] = f2bf(fmaf(v1.y, sc, sh));
    d[(pg * 8 + 6) * KS] = f2bf(fmaf(v1.z, sc, sh));
    d[(pg * 8 + 7) * KS] = f2bf(fmaf(v1.w, sc, sh));
  }
  __syncthreads();

  // --- MFMA: D[out][pos], out-tile w, pos-tiles n=0,1 ---
  const f32x4 zero4 = {0.f, 0.f, 0.f, 0.f};
#pragma unroll
  for (int n = 0; n < 2; n++) {
    const short* xr = xn_lds + (n * 16 + l16) * KS;
    bf16x8 b_lo = *(const bf16x8*)(xr + quad * 8);
    bf16x8 b_hi = *(const bf16x8*)(xr + 32 + quad * 8);
#pragma unroll
    for (int t = 0; t < 3; t++) {
      f32x4 c = zero4;
      c = __builtin_amdgcn_mfma_f32_16x16x32_bf16(a_lo[t], b_lo, c, 0, 0, 0);
      c = __builtin_amdgcn_mfma_f32_16x16x32_bf16(a_hi[t], b_hi, c, 0, 0, 0);
      i32x2 val;
      val.x = pack_bf16(c[0] + bias_r[t][0], c[1] + bias_r[t][1]);
      val.y = pack_bf16(c[2] + bias_r[t][2], c[3] + bias_r[t][3]);
      *(i32x2*)(out_lds + (n * 16 + l16) * 200 + t * 64 + wave * 16 + quad * 4) = val;
    }
  }
  __syncthreads();

  // --- write q, k: [b][pos][ch], 16B coalesced ---
  {
    const int p = tid >> 3, c8 = (tid & 7) << 3;
    short* qd = qT + ((size_t)(b * NPOS + p0 + p)) * 64 + c8;
    *(bf16x8*)qd = *(const bf16x8*)(out_lds + p * 200 + c8);
    short* kd = kT + ((size_t)(b * NPOS + p0 + p)) * 64 + c8;
    *(bf16x8*)kd = *(const bf16x8*)(out_lds + p * 200 + 64 + c8);
  }
  // --- write v: [b][ch][pos] ---
  {
    const int ch = tid >> 2, pg = tid & 3;
    bf16x8 v;
#pragma unroll
    for (int i = 0; i < 8; i++) v[i] = out_lds[(pg * 8 + i) * 200 + 128 + ch];
    *(bf16x8*)(vC + ((size_t)(b * 64 + ch)) * NPOS + p0 + pg * 8) = v;
  }
}

// ---------------- kernel 3: split-K flash attention (partials) ----------------
// grid 1024 = b(4) x chunk(4) x qtile(64). Computes S^T = K·Q^T; per-lane softmax row.
__global__ __launch_bounds__(256, 4) void flash_part_kernel(
    const short* __restrict__ qT, const short* __restrict__ kT,
    const short* __restrict__ vC, float* __restrict__ part,
    float* __restrict__ ml) {
  __shared__ short K_lds[64 * KS];      // [j_local][c]
  __shared__ short V_lds[64 * KS];      // [ch][j_local]
  __shared__ short P_lds[4 * 16 * KS];  // per wave: [m_local(16)][j(64)]

  const int blk   = blockIdx.x;
  const int qt    = blk & 63;
  const int chunk = (blk >> 6) & 3;
  const int b     = blk >> 8;
  const int q0    = qt << 6;
  const int jc    = chunk << 10;
  const int tid   = threadIdx.x;
  const int wave  = tid >> 6;
  const int lane  = tid & 63;
  const int quad  = lane >> 4;
  const int l16   = lane & 15;
  const float scale = 0.125f;

  const short* qbase = qT + ((size_t)(b * NPOS + q0 + wave * 16 + l16)) * 64;
  bf16x8 bq0 = *(const bf16x8*)(qbase + quad * 8);
  bf16x8 bq1 = *(const bf16x8*)(qbase + 32 + quad * 8);

  const f32x4 zero4 = {0.f, 0.f, 0.f, 0.f};
  f32x4 o_acc[4] = {zero4, zero4, zero4, zero4};  // O^T: ch = t*16+quad*4+r, m = l16
  float m_i = -1e30f, l_i = 0.f;

  for (int kt = 0; kt < 16; kt++) {
    const int j0 = jc + (kt << 6);
    __syncthreads();
    {
      const int r  = tid >> 2;
      const int cc = (tid & 3) << 4;
      const bf16x8* ksrc = (const bf16x8*)(kT + ((size_t)(b * NPOS + j0 + r)) * 64 + cc);
      bf16x8* kdst = (bf16x8*)(K_lds + r * KS + cc);
      kdst[0] = ksrc[0]; kdst[1] = ksrc[1];
      const bf16x8* vsrc = (const bf16x8*)(vC + ((size_t)(b * 64 + r)) * NPOS + j0 + cc);
      bf16x8* vdst = (bf16x8*)(V_lds + r * KS + cc);
      vdst[0] = vsrc[0]; vdst[1] = vsrc[1];
    }
    __syncthreads();

    f32x4 st[4];
#pragma unroll
    for (int t = 0; t < 4; t++) {
      const short* kr = K_lds + (t * 16 + l16) * KS;
      bf16x8 ka0 = *(const bf16x8*)(kr + quad * 8);
      bf16x8 ka1 = *(const bf16x8*)(kr + 32 + quad * 8);
      f32x4 acc = zero4;
      acc = __builtin_amdgcn_mfma_f32_16x16x32_bf16(ka0, bq0, acc, 0, 0, 0);
      acc = __builtin_amdgcn_mfma_f32_16x16x32_bf16(ka1, bq1, acc, 0, 0, 0);
      st[t] = acc;
    }

    float rmax = -1e30f;
#pragma unroll
    for (int t = 0; t < 4; t++)
#pragma unroll
      for (int r = 0; r < 4; r++) rmax = fmaxf(rmax, st[t][r]);
    rmax = fmaxf(rmax, __shfl_xor(rmax, 16, 64));
    rmax = fmaxf(rmax, __shfl_xor(rmax, 32, 64));
    float mn = fmaxf(m_i, rmax * scale);
    float alpha = __expf(m_i - mn);
    float rsum = 0.f;
#pragma unroll
    for (int t = 0; t < 4; t++)
#pragma unroll
      for (int r = 0; r < 4; r++) {
        float pv = __expf(st[t][r] * scale - mn);
        st[t][r] = pv;
        rsum += pv;
      }
    rsum += __shfl_xor(rsum, 16, 64);
    rsum += __shfl_xor(rsum, 32, 64);
    l_i = l_i * alpha + rsum;
    m_i = mn;
#pragma unroll
    for (int t = 0; t < 4; t++) o_acc[t] *= alpha;

    short* pw = P_lds + wave * 16 * KS;
#pragma unroll
    for (int t = 0; t < 4; t++) {
      i32x2 val;
      val.x = pack_bf16(st[t][0], st[t][1]);
      val.y = pack_bf16(st[t][2], st[t][3]);
      *(i32x2*)(pw + l16 * KS + t * 16 + quad * 4) = val;
    }
    const short* pr = pw + l16 * KS;
    bf16x8 pb0 = *(const bf16x8*)(pr + quad * 8);
    bf16x8 pb1 = *(const bf16x8*)(pr + 32 + quad * 8);

#pragma unroll
    for (int t = 0; t < 4; t++) {
      const short* vr = V_lds + (t * 16 + l16) * KS;
      bf16x8 va0 = *(const bf16x8*)(vr + quad * 8);
      bf16x8 va1 = *(const bf16x8*)(vr + 32 + quad * 8);
      o_acc[t] = __builtin_amdgcn_mfma_f32_16x16x32_bf16(va0, pb0, o_acc[t], 0, 0, 0);
      o_acc[t] = __builtin_amdgcn_mfma_f32_16x16x32_bf16(va1, pb1, o_acc[t], 0, 0, 0);
    }
  }

  const size_t pbase = ((size_t)((b * 4 + chunk) * 64 + qt)) * 4096;
  const int col = wave * 16 + l16;
#pragma unroll
  for (int t = 0; t < 4; t++)
#pragma unroll
    for (int r = 0; r < 4; r++)
      part[pbase + (size_t)(t * 16 + quad * 4 + r) * 64 + col] = o_acc[t][r];
  if (quad == 0) {
    const size_t mlbase = ((size_t)((b * 4 + chunk) * 64 + qt)) * 128;
    ml[mlbase + col]      = m_i;
    ml[mlbase + 64 + col] = l_i;
  }
}

// ---------------- kernel 4: combine partials + output conv + residual (MFMA) ----------------
// grid 512 = b(4) x pt(128 tiles of 32 Q-rows). y = x + Wo·attn + bo.
__global__ __launch_bounds__(256) void co_kernel(
    const float* __restrict__ part, const float* __restrict__ ml,
    const float* __restrict__ Wo, const float* __restrict__ bo,
    const float* __restrict__ x, float* __restrict__ y) {
  __shared__ float sm[4][32], sl[4][32], coef[4][32];
  __shared__ short attn_lds[32 * KS];  // [row][ch] bf16
  __shared__ float y_lds[64 * 36];     // [out][pos]

  const int tid   = threadIdx.x;
  const int b     = blockIdx.x >> 7;
  const int pt    = blockIdx.x & 127;
  const int qt    = pt >> 1;
  const int rhalf = (pt & 1) << 5;
  const int p0    = pt << 5;
  const int wave  = tid >> 6;
  const int lane  = tid & 63;
  const int quad  = lane >> 4;
  const int l16   = lane & 15;

  // Wo A-fragments (wave w -> out rows w*16..w*16+15)
  const float* wr = Wo + (size_t)(wave * 16 + l16) * 64;
  bf16x8 a_lo = cvt8(wr + quad * 8);
  bf16x8 a_hi = cvt8(wr + 32 + quad * 8);

  if (tid < 128) {
    const int c = tid >> 5, r = tid & 31;
    const size_t mlbase = ((size_t)((b * 4 + c) * 64 + qt)) * 128;
    sm[c][r] = ml[mlbase + rhalf + r];
    sl[c][r] = ml[mlbase + 64 + rhalf + r];
  }
  __syncthreads();
  if (tid < 32) {
    float m0 = sm[0][tid], m1 = sm[1][tid], m2 = sm[2][tid], m3 = sm[3][tid];
    float ms = fmaxf(fmaxf(m0, m1), fmaxf(m2, m3));
    float w0 = __expf(m0 - ms), w1 = __expf(m1 - ms);
    float w2 = __expf(m2 - ms), w3 = __expf(m3 - ms);
    float lt = w0 * sl[0][tid] + w1 * sl[1][tid] + w2 * sl[2][tid] + w3 * sl[3][tid];
    float inv = 1.f / lt;
    coef[0][tid] = w0 * inv; coef[1][tid] = w1 * inv;
    coef[2][tid] = w2 * inv; coef[3][tid] = w3 * inv;
  }
  __syncthreads();

  // combine partials -> attn_lds[row][ch] bf16
  {
    const int ch = tid >> 2, g = tid & 3;
    float acc[8];
#pragma unroll
    for (int i = 0; i < 8; i++) acc[i] = 0.f;
#pragma unroll
    for (int c = 0; c < 4; c++) {
      const f32x4* src = (const f32x4*)(part +
          ((size_t)((b * 4 + c) * 64 + qt)) * 4096 + (size_t)ch * 64 + rhalf + g * 8);
      f32x4 v0 = src[0], v1 = src[1];
      const float* cf = &coef[c][g * 8];
      acc[0] = fmaf(cf[0], v0.x, acc[0]); acc[1] = fmaf(cf[1], v0.y, acc[1]);
      acc[2] = fmaf(cf[2], v0.z, acc[2]); acc[3] = fmaf(cf[3], v0.w, acc[3]);
      acc[4] = fmaf(cf[4], v1.x, acc[4]); acc[5] = fmaf(cf[5], v1.y, acc[5]);
      acc[6] = fmaf(cf[6], v1.z, acc[6]); acc[7] = fmaf(cf[7], v1.w, acc[7]);
    }
#pragma unroll
    for (int i = 0; i < 8; i++) attn_lds[(g * 8 + i) * KS + ch] = f2bf(acc[i]);
  }
  __syncthreads();

  // oconv MFMA: D[out 16][pos 16], n = 0,1
  const f32x4 zero4 = {0.f, 0.f, 0.f, 0.f};
#pragma unroll
  for (int n = 0; n < 2; n++) {
    const short* ar = attn_lds + (n * 16 + l16) * KS;
    bf16x8 b_lo = *(const bf16x8*)(ar + quad * 8);
    bf16x8 b_hi = *(const bf16x8*)(ar + 32 + quad * 8);
    f32x4 c = zero4;
    c = __builtin_amdgcn_mfma_f32_16x16x32_bf16(a_lo, b_lo, c, 0, 0, 0);
    c = __builtin_amdgcn_mfma_f32_16x16x32_bf16(a_hi, b_hi, c, 0, 0, 0);
#pragma unroll
    for (int r = 0; r < 4; r++)
      y_lds[(wave * 16 + quad * 4 + r) * 36 + n * 16 + l16] = c[r];
  }
  __syncthreads();

  // y = x + bo + y_lds, coalesced
  {
    const int ch = tid >> 2, pg = tid & 3;
    const size_t off = ((size_t)(b * 64 + ch)) * NPOS + p0 + pg * 8;
    const float* xs = x + off;
    float* dst = y + off;
    float bb = bo[ch];
    const float* ys = y_lds + ch * 36 + pg * 8;
    f32x4 x0 = *(const f32x4*)xs, x1 = *(const f32x4*)(xs + 4);
    f32x4 y0 = *(const f32x4*)ys, y1 = *(const f32x4*)(ys + 4);
    f32x4 o0 = {x0.x + bb + y0.x, x0.y + bb + y0.y, x0.z + bb + y0.z, x0.w + bb + y0.w};
    f32x4 o1 = {x1.x + bb + y1.x, x1.y + bb + y1.y, x1.z + bb + y1.z, x1.w + bb + y1.w};
    *(f32x4*)dst = o0;
    *(f32x4*)(dst + 4) = o1;
  }
}

// ---------------- launcher ----------------
extern "C" void kernel_launch(void* const* d_in, const int* in_sizes, int n_in,
                              void* d_out, int out_size, void* d_ws, size_t ws_size,
                              hipStream_t stream) {
  const float* x     = (const float*)d_in[0];
  const float* Wq    = (const float*)d_in[1];
  const float* bq    = (const float*)d_in[2];
  const float* Wk    = (const float*)d_in[3];
  const float* bk    = (const float*)d_in[4];
  const float* Wv    = (const float*)d_in[5];
  const float* bv    = (const float*)d_in[6];
  const float* Wo    = (const float*)d_in[7];
  const float* bo    = (const float*)d_in[8];
  const float* gamma = (const float*)d_in[9];
  const float* beta  = (const float*)d_in[10];
  float* y = (float*)d_out;

  char* ws = (char*)d_ws;
  float* stats = (float*)ws;                                   // 1 KB
  short* qT   = (short*)(ws + 1024);                           // 2 MB
  short* kT   = (short*)(ws + 1024 + (1u << 21));              // 2 MB
  short* vC   = (short*)(ws + 1024 + (2u << 21));              // 2 MB
  float* part = (float*)(ws + 1024 + (3u << 21));              // 16 MB [b][chunk][qt][ch][row]
  float* ml   = (float*)(ws + 1024 + (11u << 21));             // 512 KB

  stats_kernel<<<dim3(128), dim3(256), 0, stream>>>(x, stats);
  qkv_kernel<<<dim3(512), dim3(256), 0, stream>>>(x, Wq, bq, Wk, bk, Wv, bv,
                                                  gamma, beta, stats, qT, kT, vC);
  flash_part_kernel<<<dim3(1024), dim3(256), 0, stream>>>(qT, kT, vC, part, ml);
  co_kernel<<<dim3(512), dim3(256), 0, stream>>>(part, ml, Wo, bo, x, y);
}